// Round 5
// baseline (225.290 us; speedup 1.0000x reference)
//
#include <hip/hip_runtime.h>
#include <hip/hip_bf16.h>

#define D_FEAT 128
#define D2 (D_FEAT / 2)   // 64 float2 / bf162 per row
#define D4 (D_FEAT / 4)   // 32 float4 per row
#define SCAN_BLOCK 1024

// ---------- preprocessing ----------

__global__ void hist_kernel(const int* __restrict__ dst, int* __restrict__ counts, int E) {
    int i = (blockIdx.x * blockDim.x + threadIdx.x) * 4;
    if (i + 3 < E) {
        int4 d = *(const int4*)(dst + i);
        atomicAdd(&counts[d.x], 1);
        atomicAdd(&counts[d.y], 1);
        atomicAdd(&counts[d.z], 1);
        atomicAdd(&counts[d.w], 1);
    } else {
        for (int e = i; e < E; e++) atomicAdd(&counts[dst[e]], 1);
    }
}

__global__ void block_sums_kernel(const int* __restrict__ counts,
                                  int* __restrict__ blocksums, int n) {
    __shared__ int sdata[SCAN_BLOCK];
    int tid = threadIdx.x;
    int i = blockIdx.x * SCAN_BLOCK + tid;
    sdata[tid] = (i < n) ? counts[i] : 0;
    __syncthreads();
    for (int off = SCAN_BLOCK / 2; off > 0; off >>= 1) {
        if (tid < off) sdata[tid] += sdata[tid + off];
        __syncthreads();
    }
    if (tid == 0) blocksums[blockIdx.x] = sdata[0];
}

__global__ void scan_sums_kernel(int* __restrict__ blocksums, int nb) {
    __shared__ int sdata[256];
    int tid = threadIdx.x;
    int v = (tid < nb) ? blocksums[tid] : 0;
    sdata[tid] = v;
    __syncthreads();
    for (int off = 1; off < 256; off <<= 1) {
        int t = (tid >= off) ? sdata[tid - off] : 0;
        __syncthreads();
        sdata[tid] += t;
        __syncthreads();
    }
    if (tid < nb) blocksums[tid] = sdata[tid] - v;  // exclusive
}

__global__ void local_scan_kernel(const int* __restrict__ counts,
                                  const int* __restrict__ blocksums,
                                  int* __restrict__ offsets,
                                  int* __restrict__ cursors, int n, int total) {
    __shared__ int sdata[SCAN_BLOCK];
    int tid = threadIdx.x;
    int i = blockIdx.x * SCAN_BLOCK + tid;
    int v = (i < n) ? counts[i] : 0;
    sdata[tid] = v;
    __syncthreads();
    for (int off = 1; off < SCAN_BLOCK; off <<= 1) {
        int t = (tid >= off) ? sdata[tid - off] : 0;
        __syncthreads();
        sdata[tid] += t;
        __syncthreads();
    }
    if (i < n) {
        int off = blocksums[blockIdx.x] + sdata[tid] - v;
        offsets[i] = off;
        cursors[i] = off;
    }
    if (blockIdx.x == 0 && tid == 0) offsets[n] = total;
}

__global__ void scatter_kernel(const int* __restrict__ src,
                               const int* __restrict__ dst,
                               const float* __restrict__ vals,
                               int* __restrict__ cursors,
                               int2* __restrict__ spack, int E) {
    int i = (blockIdx.x * blockDim.x + threadIdx.x) * 4;
    if (i + 3 < E) {
        int4 s = *(const int4*)(src + i);
        int4 d = *(const int4*)(dst + i);
        float4 v = *(const float4*)(vals + i);
        int p0 = atomicAdd(&cursors[d.x], 1);
        int p1 = atomicAdd(&cursors[d.y], 1);
        int p2 = atomicAdd(&cursors[d.z], 1);
        int p3 = atomicAdd(&cursors[d.w], 1);
        spack[p0] = make_int2(s.x, __float_as_int(v.x));
        spack[p1] = make_int2(s.y, __float_as_int(v.y));
        spack[p2] = make_int2(s.z, __float_as_int(v.z));
        spack[p3] = make_int2(s.w, __float_as_int(v.w));
    } else {
        for (int e = i; e < E; e++) {
            int pos = atomicAdd(&cursors[dst[e]], 1);
            spack[pos] = make_int2(src[e], __float_as_int(vals[e]));
        }
    }
}

// fp32 features -> bf16 table in workspace
__global__ void cvt_kernel(const float4* __restrict__ in,
                           __hip_bfloat162* __restrict__ out, int n4) {
    int i = blockIdx.x * blockDim.x + threadIdx.x;
    if (i < n4) {
        float4 f = in[i];
        out[2 * i + 0] = __float22bfloat162_rn(make_float2(f.x, f.y));
        out[2 * i + 1] = __float22bfloat162_rn(make_float2(f.z, f.w));
    }
}

// ---------- gather (bf16 features, fp32 accumulate) ----------
// One wave per node; lane l holds features [2l, 2l+1].
__global__ void gather_bf16_kernel(const int* __restrict__ offsets,
                                   const int2* __restrict__ spack,
                                   const __hip_bfloat162* __restrict__ feat,
                                   const float2* __restrict__ bias2,
                                   float2* __restrict__ out2,
                                   int n_nodes) {
    int gtid = blockIdx.x * blockDim.x + threadIdx.x;
    int node = gtid >> 6;
    int lane = gtid & 63;
    if (node >= n_nodes) return;

    int beg = offsets[node];
    int end = offsets[node + 1];
    float2 acc0 = bias2[lane];
    float2 acc1 = make_float2(0.f, 0.f);

    int e = beg;
    for (; e + 8 <= end; e += 8) {
        int2 p[8];
        __hip_bfloat162 h[8];
#pragma unroll
        for (int j = 0; j < 8; j++) p[j] = spack[e + j];
#pragma unroll
        for (int j = 0; j < 8; j++) h[j] = feat[(size_t)p[j].x * D2 + lane];
#pragma unroll
        for (int j = 0; j < 8; j++) {
            float v = __int_as_float(p[j].y);
            float2 f = __bfloat1622float2(h[j]);
            if (j & 1) { acc1.x += v * f.x; acc1.y += v * f.y; }
            else       { acc0.x += v * f.x; acc0.y += v * f.y; }
        }
    }
    for (; e < end; e++) {
        int2 p = spack[e];
        float v = __int_as_float(p.y);
        float2 f = __bfloat1622float2(feat[(size_t)p.x * D2 + lane]);
        acc0.x += v * f.x; acc0.y += v * f.y;
    }
    acc0.x += acc1.x; acc0.y += acc1.y;
    out2[(size_t)node * D2 + lane] = acc0;
}

// fp32-feature gather (fallback if ws too small for bf16 table)
__global__ void gather_kernel(const int* __restrict__ offsets,
                              const int2* __restrict__ spack,
                              const float2* __restrict__ feat2,
                              const float2* __restrict__ bias2,
                              float2* __restrict__ out2,
                              int n_nodes) {
    int gtid = blockIdx.x * blockDim.x + threadIdx.x;
    int node = gtid >> 6;
    int lane = gtid & 63;
    if (node >= n_nodes) return;

    int beg = offsets[node];
    int end = offsets[node + 1];
    float2 acc0 = bias2[lane];
    float2 acc1 = make_float2(0.f, 0.f);

    int e = beg;
    for (; e + 4 <= end; e += 4) {
        int2 p0 = spack[e + 0];
        int2 p1 = spack[e + 1];
        int2 p2 = spack[e + 2];
        int2 p3 = spack[e + 3];
        float2 f0 = feat2[(size_t)p0.x * D2 + lane];
        float2 f1 = feat2[(size_t)p1.x * D2 + lane];
        float2 f2 = feat2[(size_t)p2.x * D2 + lane];
        float2 f3 = feat2[(size_t)p3.x * D2 + lane];
        float v0 = __int_as_float(p0.y);
        float v1 = __int_as_float(p1.y);
        float v2 = __int_as_float(p2.y);
        float v3 = __int_as_float(p3.y);
        acc0.x += v0 * f0.x; acc0.y += v0 * f0.y;
        acc1.x += v1 * f1.x; acc1.y += v1 * f1.y;
        acc0.x += v2 * f2.x; acc0.y += v2 * f2.y;
        acc1.x += v3 * f3.x; acc1.y += v3 * f3.y;
    }
    for (; e < end; e++) {
        int2 p = spack[e];
        float v = __int_as_float(p.y);
        float2 f = feat2[(size_t)p.x * D2 + lane];
        acc0.x += v * f.x; acc0.y += v * f.y;
    }
    acc0.x += acc1.x; acc0.y += acc1.y;
    out2[(size_t)node * D2 + lane] = acc0;
}

// ---------- fallback atomic path ----------

__global__ void init_bias_kernel(float4* __restrict__ out,
                                 const float4* __restrict__ bias, int n4) {
    int i = blockIdx.x * blockDim.x + threadIdx.x;
    if (i < n4) out[i] = bias[i & (D4 - 1)];
}

__global__ void spmm_edge_kernel(const int* __restrict__ src,
                                 const int* __restrict__ dst,
                                 const float* __restrict__ vals,
                                 const float4* __restrict__ feat,
                                 float* __restrict__ out, int n_edges) {
    int tid = blockIdx.x * blockDim.x + threadIdx.x;
    int e = tid >> 5;
    int lane = tid & 31;
    if (e >= n_edges) return;
    int s = src[e];
    int d = dst[e];
    float v = vals[e];
    float4 f = feat[(size_t)s * D4 + lane];
    float* o = out + (size_t)d * D_FEAT + lane * 4;
    atomicAdd(o + 0, v * f.x);
    atomicAdd(o + 1, v * f.y);
    atomicAdd(o + 2, v * f.z);
    atomicAdd(o + 3, v * f.w);
}

extern "C" void kernel_launch(void* const* d_in, const int* in_sizes, int n_in,
                              void* d_out, int out_size, void* d_ws, size_t ws_size,
                              hipStream_t stream) {
    const int* edge_index = (const int*)d_in[0];    // (2, E) int32
    const float* edge_vals = (const float*)d_in[1]; // (E,)
    const float* features  = (const float*)d_in[2]; // (N, 128)
    const float* bias      = (const float*)d_in[3]; // (128,)

    int E = in_sizes[1];
    int N = in_sizes[2] / D_FEAT;
    const int* src = edge_index;
    const int* dst = edge_index + E;
    float* out = (float*)d_out;

    int NB = (N + SCAN_BLOCK - 1) / SCAN_BLOCK;

    // ws layout: fb16[N*128] bf16 | spack[E] int2 | offsets[N+1] | cursors[N]
    //            | counts[N] | blocksums[NB]
    size_t sort_ints = (size_t)2 * E + 3 * N + 1 + NB;
    size_t needed_bf16 = (size_t)N * D_FEAT * 2 + sort_ints * sizeof(int);
    size_t needed_sort = sort_ints * sizeof(int);

    if (ws_size >= needed_sort && NB <= 256) {
        bool use_bf16 = (ws_size >= needed_bf16);
        char* wp = (char*)d_ws;
        __hip_bfloat162* fb16 = nullptr;
        if (use_bf16) {
            fb16 = (__hip_bfloat162*)wp;
            wp += (size_t)N * D_FEAT * 2;
        }
        int2* spack  = (int2*)wp;
        int* offsets = (int*)(spack + E);
        int* cursors = offsets + (N + 1);
        int* counts  = cursors + N;
        int* blocksums = counts + N;

        hipMemsetAsync(counts, 0, (size_t)N * sizeof(int), stream);
        if (use_bf16) {
            int n4 = N * D_FEAT / 4;
            int block = 256, grid = (n4 + block - 1) / block;
            cvt_kernel<<<grid, block, 0, stream>>>((const float4*)features, fb16, n4);
        }
        {
            int block = 256, grid = (E / 4 + block - 1) / block;
            hist_kernel<<<grid, block, 0, stream>>>(dst, counts, E);
        }
        block_sums_kernel<<<NB, SCAN_BLOCK, 0, stream>>>(counts, blocksums, N);
        scan_sums_kernel<<<1, 256, 0, stream>>>(blocksums, NB);
        local_scan_kernel<<<NB, SCAN_BLOCK, 0, stream>>>(counts, blocksums,
                                                         offsets, cursors, N, E);
        {
            int block = 256, grid = (E / 4 + block - 1) / block;
            scatter_kernel<<<grid, block, 0, stream>>>(src, dst, edge_vals,
                                                       cursors, spack, E);
        }
        {
            long long total = (long long)N * 64;
            int block = 256;
            int grid = (int)((total + block - 1) / block);
            if (use_bf16) {
                gather_bf16_kernel<<<grid, block, 0, stream>>>(offsets, spack, fb16,
                                                               (const float2*)bias,
                                                               (float2*)out, N);
            } else {
                gather_kernel<<<grid, block, 0, stream>>>(offsets, spack,
                                                          (const float2*)features,
                                                          (const float2*)bias,
                                                          (float2*)out, N);
            }
        }
    } else {
        int n4 = out_size / 4;
        {
            int block = 256, grid = (n4 + block - 1) / block;
            init_bias_kernel<<<grid, block, 0, stream>>>((float4*)out,
                                                         (const float4*)bias, n4);
        }
        {
            int block = 256;
            long long total = (long long)E * 32;
            int grid = (int)((total + block - 1) / block);
            spmm_edge_kernel<<<grid, block, 0, stream>>>(src, dst, edge_vals,
                                                         (const float4*)features,
                                                         out, E);
        }
    }
}

// Round 6
// 213.900 us; speedup vs baseline: 1.0532x; 1.0532x over previous
//
#include <hip/hip_runtime.h>
#include <hip/hip_bf16.h>

#define D_FEAT 128
#define D2 (D_FEAT / 2)   // 64 bf162/float2 per row
#define D4 (D_FEAT / 4)
#define SCAN_BLOCK 1024
#define PAD 16            // one counter per 64B line to kill atomic line contention

// ---------- preprocessing ----------

// fused: threads [0,E) histogram dst into strided counts; [E, E+n4) convert fp32->bf16
__global__ void hist_cvt_kernel(const int* __restrict__ dst,
                                int* __restrict__ counts, int pad, int E,
                                const float4* __restrict__ fin,
                                __hip_bfloat162* __restrict__ fout, int n4) {
    int t = blockIdx.x * blockDim.x + threadIdx.x;
    if (t < E) {
        atomicAdd(&counts[dst[t] * pad], 1);
    } else {
        int i = t - E;
        if (i < n4) {
            float4 f = fin[i];
            fout[2 * i + 0] = __float22bfloat162_rn(make_float2(f.x, f.y));
            fout[2 * i + 1] = __float22bfloat162_rn(make_float2(f.z, f.w));
        }
    }
}

__global__ void block_sums_kernel(const int* __restrict__ counts, int pad,
                                  int* __restrict__ blocksums, int n) {
    __shared__ int sdata[SCAN_BLOCK];
    int tid = threadIdx.x;
    int i = blockIdx.x * SCAN_BLOCK + tid;
    sdata[tid] = (i < n) ? counts[(size_t)i * pad] : 0;
    __syncthreads();
    for (int off = SCAN_BLOCK / 2; off > 0; off >>= 1) {
        if (tid < off) sdata[tid] += sdata[tid + off];
        __syncthreads();
    }
    if (tid == 0) blocksums[blockIdx.x] = sdata[0];
}

__global__ void scan_sums_kernel(int* __restrict__ blocksums, int nb) {
    __shared__ int sdata[256];
    int tid = threadIdx.x;
    int v = (tid < nb) ? blocksums[tid] : 0;
    sdata[tid] = v;
    __syncthreads();
    for (int off = 1; off < 256; off <<= 1) {
        int t = (tid >= off) ? sdata[tid - off] : 0;
        __syncthreads();
        sdata[tid] += t;
        __syncthreads();
    }
    if (tid < nb) blocksums[tid] = sdata[tid] - v;  // exclusive
}

// local exclusive scan; writes offsets[i] and overwrites counts[i*pad] with the
// same prefix (counts becomes the scatter cursor array, in place).
__global__ void local_scan_kernel(int* __restrict__ counts, int pad,
                                  const int* __restrict__ blocksums,
                                  int* __restrict__ offsets, int n, int total) {
    __shared__ int sdata[SCAN_BLOCK];
    int tid = threadIdx.x;
    int i = blockIdx.x * SCAN_BLOCK + tid;
    int v = (i < n) ? counts[(size_t)i * pad] : 0;
    sdata[tid] = v;
    __syncthreads();
    for (int off = 1; off < SCAN_BLOCK; off <<= 1) {
        int t = (tid >= off) ? sdata[tid - off] : 0;
        __syncthreads();
        sdata[tid] += t;
        __syncthreads();
    }
    if (i < n) {
        int off = blocksums[blockIdx.x] + sdata[tid] - v;
        offsets[i] = off;
        counts[(size_t)i * pad] = off;
    }
    if (blockIdx.x == 0 && tid == 0) offsets[n] = total;
}

__global__ void scatter_kernel(const int* __restrict__ src,
                               const int* __restrict__ dst,
                               const float* __restrict__ vals,
                               int* __restrict__ cursors, int pad,
                               int2* __restrict__ spack, int E) {
    int e = blockIdx.x * blockDim.x + threadIdx.x;
    if (e < E) {
        int pos = atomicAdd(&cursors[dst[e] * pad], 1);
        spack[pos] = make_int2(src[e], __float_as_int(vals[e]));
    }
}

// ---------- gather (bf16 features, fp32 accumulate) ----------
__global__ void gather_bf16_kernel(const int* __restrict__ offsets,
                                   const int2* __restrict__ spack,
                                   const __hip_bfloat162* __restrict__ feat,
                                   const float2* __restrict__ bias2,
                                   float2* __restrict__ out2, int n_nodes) {
    int gtid = blockIdx.x * blockDim.x + threadIdx.x;
    int node = gtid >> 6;
    int lane = gtid & 63;
    if (node >= n_nodes) return;

    int beg = offsets[node];
    int end = offsets[node + 1];
    float2 acc0 = bias2[lane];
    float2 acc1 = make_float2(0.f, 0.f);

    int e = beg;
    for (; e + 8 <= end; e += 8) {
        int2 p[8];
        __hip_bfloat162 h[8];
#pragma unroll
        for (int j = 0; j < 8; j++) p[j] = spack[e + j];
#pragma unroll
        for (int j = 0; j < 8; j++) h[j] = feat[(size_t)p[j].x * D2 + lane];
#pragma unroll
        for (int j = 0; j < 8; j++) {
            float v = __int_as_float(p[j].y);
            float2 f = __bfloat1622float2(h[j]);
            if (j & 1) { acc1.x += v * f.x; acc1.y += v * f.y; }
            else       { acc0.x += v * f.x; acc0.y += v * f.y; }
        }
    }
    for (; e < end; e++) {
        int2 p = spack[e];
        float v = __int_as_float(p.y);
        float2 f = __bfloat1622float2(feat[(size_t)p.x * D2 + lane]);
        acc0.x += v * f.x; acc0.y += v * f.y;
    }
    acc0.x += acc1.x; acc0.y += acc1.y;
    out2[(size_t)node * D2 + lane] = acc0;
}

// fp32-feature gather (ws too small for bf16 table)
__global__ void gather_kernel(const int* __restrict__ offsets,
                              const int2* __restrict__ spack,
                              const float2* __restrict__ feat2,
                              const float2* __restrict__ bias2,
                              float2* __restrict__ out2, int n_nodes) {
    int gtid = blockIdx.x * blockDim.x + threadIdx.x;
    int node = gtid >> 6;
    int lane = gtid & 63;
    if (node >= n_nodes) return;

    int beg = offsets[node];
    int end = offsets[node + 1];
    float2 acc0 = bias2[lane];
    float2 acc1 = make_float2(0.f, 0.f);

    int e = beg;
    for (; e + 4 <= end; e += 4) {
        int2 p0 = spack[e + 0];
        int2 p1 = spack[e + 1];
        int2 p2 = spack[e + 2];
        int2 p3 = spack[e + 3];
        float2 f0 = feat2[(size_t)p0.x * D2 + lane];
        float2 f1 = feat2[(size_t)p1.x * D2 + lane];
        float2 f2 = feat2[(size_t)p2.x * D2 + lane];
        float2 f3 = feat2[(size_t)p3.x * D2 + lane];
        acc0.x += __int_as_float(p0.y) * f0.x; acc0.y += __int_as_float(p0.y) * f0.y;
        acc1.x += __int_as_float(p1.y) * f1.x; acc1.y += __int_as_float(p1.y) * f1.y;
        acc0.x += __int_as_float(p2.y) * f2.x; acc0.y += __int_as_float(p2.y) * f2.y;
        acc1.x += __int_as_float(p3.y) * f3.x; acc1.y += __int_as_float(p3.y) * f3.y;
    }
    for (; e < end; e++) {
        int2 p = spack[e];
        float v = __int_as_float(p.y);
        float2 f = feat2[(size_t)p.x * D2 + lane];
        acc0.x += v * f.x; acc0.y += v * f.y;
    }
    acc0.x += acc1.x; acc0.y += acc1.y;
    out2[(size_t)node * D2 + lane] = acc0;
}

// ---------- fallback atomic path ----------

__global__ void init_bias_kernel(float4* __restrict__ out,
                                 const float4* __restrict__ bias, int n4) {
    int i = blockIdx.x * blockDim.x + threadIdx.x;
    if (i < n4) out[i] = bias[i & (D4 - 1)];
}

__global__ void spmm_edge_kernel(const int* __restrict__ src,
                                 const int* __restrict__ dst,
                                 const float* __restrict__ vals,
                                 const float4* __restrict__ feat,
                                 float* __restrict__ out, int n_edges) {
    int tid = blockIdx.x * blockDim.x + threadIdx.x;
    int e = tid >> 5;
    int lane = tid & 31;
    if (e >= n_edges) return;
    int s = src[e];
    int d = dst[e];
    float v = vals[e];
    float4 f = feat[(size_t)s * D4 + lane];
    float* o = out + (size_t)d * D_FEAT + lane * 4;
    atomicAdd(o + 0, v * f.x);
    atomicAdd(o + 1, v * f.y);
    atomicAdd(o + 2, v * f.z);
    atomicAdd(o + 3, v * f.w);
}

extern "C" void kernel_launch(void* const* d_in, const int* in_sizes, int n_in,
                              void* d_out, int out_size, void* d_ws, size_t ws_size,
                              hipStream_t stream) {
    const int* edge_index = (const int*)d_in[0];    // (2, E) int32
    const float* edge_vals = (const float*)d_in[1]; // (E,)
    const float* features  = (const float*)d_in[2]; // (N, 128)
    const float* bias      = (const float*)d_in[3]; // (128,)

    int E = in_sizes[1];
    int N = in_sizes[2] / D_FEAT;
    const int* src = edge_index;
    const int* dst = edge_index + E;
    float* out = (float*)d_out;

    int NB = (N + SCAN_BLOCK - 1) / SCAN_BLOCK;
    int n4 = N * D_FEAT / 4;

    // ws layout: [fb16 N*128 bf16]? | spack[E] int2 | offsets[N+1] | countcur[N*pad] | blocksums[NB]
    auto need = [&](int pad, bool bf16) -> size_t {
        size_t b = bf16 ? (size_t)N * D_FEAT * 2 : 0;
        return b + (size_t)E * 8 + ((size_t)(N + 1) + (size_t)N * pad + NB) * 4;
    };

    int pad;
    bool use_bf16;
    if      (ws_size >= need(PAD, true))  { pad = PAD; use_bf16 = true;  }
    else if (ws_size >= need(1,   true))  { pad = 1;   use_bf16 = true;  }
    else if (ws_size >= need(1,   false)) { pad = 1;   use_bf16 = false; }
    else                                   { pad = 0;   use_bf16 = false; }

    if (pad > 0 && NB <= 256) {
        char* wp = (char*)d_ws;
        __hip_bfloat162* fb16 = nullptr;
        if (use_bf16) { fb16 = (__hip_bfloat162*)wp; wp += (size_t)N * D_FEAT * 2; }
        int2* spack   = (int2*)wp;
        int* offsets  = (int*)(spack + E);
        int* countcur = offsets + (N + 1);
        int* blocksums = countcur + (size_t)N * pad;

        hipMemsetAsync(countcur, 0, (size_t)N * pad * sizeof(int), stream);

        {
            int total = E + (use_bf16 ? n4 : 0);
            int block = 256, grid = (total + block - 1) / block;
            hist_cvt_kernel<<<grid, block, 0, stream>>>(dst, countcur, pad, E,
                                                        (const float4*)features,
                                                        fb16, use_bf16 ? n4 : 0);
        }
        block_sums_kernel<<<NB, SCAN_BLOCK, 0, stream>>>(countcur, pad, blocksums, N);
        scan_sums_kernel<<<1, 256, 0, stream>>>(blocksums, NB);
        local_scan_kernel<<<NB, SCAN_BLOCK, 0, stream>>>(countcur, pad, blocksums,
                                                         offsets, N, E);
        {
            int block = 256, grid = (E + block - 1) / block;
            scatter_kernel<<<grid, block, 0, stream>>>(src, dst, edge_vals,
                                                       countcur, pad, spack, E);
        }
        {
            long long total = (long long)N * 64;
            int block = 256;
            int grid = (int)((total + block - 1) / block);
            if (use_bf16) {
                gather_bf16_kernel<<<grid, block, 0, stream>>>(offsets, spack, fb16,
                                                               (const float2*)bias,
                                                               (float2*)out, N);
            } else {
                gather_kernel<<<grid, block, 0, stream>>>(offsets, spack,
                                                          (const float2*)features,
                                                          (const float2*)bias,
                                                          (float2*)out, N);
            }
        }
    } else {
        int no4 = out_size / 4;
        {
            int block = 256, grid = (no4 + block - 1) / block;
            init_bias_kernel<<<grid, block, 0, stream>>>((float4*)out,
                                                         (const float4*)bias, no4);
        }
        {
            int block = 256;
            long long total = (long long)E * 32;
            int grid = (int)((total + block - 1) / block);
            spmm_edge_kernel<<<grid, block, 0, stream>>>(src, dst, edge_vals,
                                                         (const float4*)features,
                                                         out, E);
        }
    }
}